// Round 8
// baseline (140.681 us; speedup 1.0000x reference)
//
#include <hip/hip_runtime.h>
#include <hip/hip_bf16.h>

#define IN_C  32
#define CH    35
#define P_CNT 369
#define NPAIR 64
#define NALL  100000
#define NTILE 6250          // NALL / 16 exactly
#define PP    4             // pairs per wave (grid.y = 64/PP = 16)
#define NWX   784           // grid.x(196) * 4 waves/block

// param offsets within a proposal's 369 floats
#define OW1 0               // w1[c][h] = c*8 + h   (c < 35)
#define OB1 280
#define OW2 288             // w2[h][k] = 288 + h*8 + k
#define OB2 352
#define OW3 360
#define OB3 368

// d_ws byte offsets
#define WS_W1F 0            // ushort [64 pair][2 kh][64 lane][8]   131072 B
#define WS_W2F 131072       // ushort [64][64 lane][4]              32768 B
#define WS_B1F 163840       // float  [64][64 lane][4]              65536 B
#define WS_B2F 229376       // float  [64][64 lane][4]              65536 B
#define WS_W3F 294912       // float  [64][64 lane][4]              65536 B
#define WS_B3F 360448       // float  [64][2]                       512 B

typedef short  bf16x8 __attribute__((ext_vector_type(8)));
typedef short  bf16x4 __attribute__((ext_vector_type(4)));
typedef float  f32x4  __attribute__((ext_vector_type(4)));

static __device__ inline unsigned short f2bf(float x) {   // software RNE (prep + fallback)
    union { float f; unsigned u; } v; v.f = x;
    unsigned r = v.u + 0x7FFFu + ((v.u >> 16) & 1u);
    return (unsigned short)(r >> 16);
}

// API-sanctioned packed f32->bf16 RNE (native cvt on gfx950).
static __device__ inline unsigned pack2bf(float lo, float hi) {
    __hip_bfloat162 h2 = __float22bfloat162_rn(make_float2(lo, hi));
    union { __hip_bfloat162 h; unsigned u; } c; c.h = h2; return c.u;
}

// ---------------- Prep: params for one pair + lane-exact fragment packing ----
__global__ __launch_bounds__(256) void prep_kernel(
        const float* __restrict__ prop,   // (128, 32)
        const float* __restrict__ W,      // (32, 369)
        const float* __restrict__ b,      // (369,)
        char* __restrict__ ws) {
    const int pp  = blockIdx.x;           // pair index 0..63
    const int tid = threadIdx.x;
    __shared__ float P[2][P_CNT];

    for (int idx = tid; idx < 2 * P_CNT; idx += 256) {
        const int pl = (idx >= P_CNT) ? 1 : 0;
        const int j  = idx - pl * P_CNT;
        const float* pr = prop + (size_t)(2 * pp + pl) * IN_C;
        float acc = b[j];
        #pragma unroll
        for (int c = 0; c < IN_C; ++c)
            acc = fmaf(pr[c], W[(size_t)c * P_CNT + j], acc);
        P[pl][j] = acc;
    }
    __syncthreads();

    if (tid >= 64) return;
    const int lane = tid;
    const int g = lane >> 4;
    const int m = lane & 15;

    // W1F: A-frag of 16x16x32. A[m = h-packed][k = c]; lane: row=m, k=8g+j
    {
        unsigned short* w1f = (unsigned short*)(ws + WS_W1F);
        const int pl = m >> 3, h = m & 7;
        #pragma unroll
        for (int kh = 0; kh < 2; ++kh)
            #pragma unroll
            for (int j = 0; j < 8; ++j) {
                const int c = kh * 32 + g * 8 + j;
                const float v = (c < CH) ? P[pl][OW1 + c * 8 + h] : 0.f;
                w1f[((size_t)(pp * 2 + kh) * 64 + lane) * 8 + j] = f2bf(v);
            }
    }
    // W2F: A-frag of 16x16x16 (block-diag packed w2). row=m, k=4g+r
    {
        unsigned short* w2f = (unsigned short*)(ws + WS_W2F);
        const int plj = m >> 3, jj = m & 7;
        #pragma unroll
        for (int r = 0; r < 4; ++r) {
            const int colh = g * 4 + r;
            const int ph = colh >> 3, h = colh & 7;
            const float v = (ph == plj) ? P[plj][OW2 + h * 8 + jj] : 0.f;
            w2f[((size_t)pp * 64 + lane) * 4 + r] = f2bf(v);
        }
    }
    // B1F / B2F / W3F: per-lane C-init rows (row = 4g + r, h/j-packed)
    {
        float* b1f = (float*)(ws + WS_B1F);
        float* b2f = (float*)(ws + WS_B2F);
        float* w3f = (float*)(ws + WS_W3F);
        #pragma unroll
        for (int r = 0; r < 4; ++r) {
            const int row = g * 4 + r;
            b1f[((size_t)pp * 64 + lane) * 4 + r] = P[row >> 3][OB1 + (row & 7)];
            b2f[((size_t)pp * 64 + lane) * 4 + r] = P[row >> 3][OB2 + (row & 7)];
            w3f[((size_t)pp * 64 + lane) * 4 + r] = P[row >> 3][OW3 + (row & 7)];
        }
    }
    if (lane < 2) ((float*)(ws + WS_B3F))[pp * 2 + lane] = P[lane][OB3];
}

// Load one 16-row feature tile's B-fragments for this lane.
// bf0: k = 8g+j (c 0..31); bf1: k = 32+8g+j (only g==0, j<3 nonzero: c 32..34).
#define LOAD_TILE(T, O0, O1) do {                                             \
    const float* fr_ = allf + (size_t)((T) * 16 + col) * CH;                  \
    const float v0_ = fr_[g * 8 + 0], v1_ = fr_[g * 8 + 1];                   \
    const float v2_ = fr_[g * 8 + 2], v3_ = fr_[g * 8 + 3];                   \
    const float v4_ = fr_[g * 8 + 4], v5_ = fr_[g * 8 + 5];                   \
    const float v6_ = fr_[g * 8 + 6], v7_ = fr_[g * 8 + 7];                   \
    float e0_ = 0.f, e1_ = 0.f, e2_ = 0.f;                                    \
    if (g == 0) { e0_ = fr_[32]; e1_ = fr_[33]; e2_ = fr_[34]; }              \
    union { unsigned u[4]; bf16x8 v; } A0_, A1_;                              \
    A0_.u[0] = pack2bf(v0_, v1_); A0_.u[1] = pack2bf(v2_, v3_);               \
    A0_.u[2] = pack2bf(v4_, v5_); A0_.u[3] = pack2bf(v6_, v7_);               \
    A1_.u[0] = pack2bf(e0_, e1_); A1_.u[1] = pack2bf(e2_, 0.f);               \
    A1_.u[2] = 0u; A1_.u[3] = 0u;                                             \
    O0 = A0_.v; O1 = A1_.v; } while (0)

// ---------------- Main: weights-resident (PP pairs in regs), stream tiles ---
__global__ __launch_bounds__(256, 3) void mlp_kernel(
        const float* __restrict__ allf,   // (100000, 35)
        const char* __restrict__ ws,
        float* __restrict__ out) {        // (128, 100000)
    const int lane = threadIdx.x & 63;
    const int wave = threadIdx.x >> 6;
    const int wx   = blockIdx.x * 4 + wave;   // 0..NWX-1
    const int g    = lane >> 4;
    const int col  = lane & 15;
    const int ppbase = blockIdx.y * PP;

    const bf16x8* __restrict__ w1f = (const bf16x8*)(ws + WS_W1F);
    const bf16x4* __restrict__ w2f = (const bf16x4*)(ws + WS_W2F);
    const f32x4*  __restrict__ b1f = (const f32x4*)(ws + WS_B1F);
    const f32x4*  __restrict__ b2f = (const f32x4*)(ws + WS_B2F);
    const f32x4*  __restrict__ w3f = (const f32x4*)(ws + WS_W3F);
    const float*  __restrict__ b3f = (const float*)(ws + WS_B3F);

    // ---- resident weights for PP pairs (~96 VGPR), loaded once ----
    bf16x8 w1a[PP], w1b[PP];
    bf16x4 w2v[PP];
    f32x4  b1v[PP], b2v[PP], w3v[PP];
    float  b3s[PP];
    #pragma unroll
    for (int i = 0; i < PP; ++i) {
        const int pp = ppbase + i;
        w1a[i] = w1f[(pp * 2 + 0) * 64 + lane];
        w1b[i] = w1f[(pp * 2 + 1) * 64 + lane];
        w2v[i] = w2f[pp * 64 + lane];
        b1v[i] = b1f[pp * 64 + lane];
        b2v[i] = b2f[pp * 64 + lane];
        w3v[i] = w3f[pp * 64 + lane];
        b3s[i] = b3f[pp * 2 + (lane >> 5)];
    }
    #pragma unroll
    for (int i = 0; i < PP; ++i)
        asm volatile("" : "+v"(w1a[i]), "+v"(w1b[i]), "+v"(w2v[i]),
                          "+v"(b1v[i]), "+v"(b2v[i]), "+v"(w3v[i]));

    if (wx >= NTILE) return;

    // ---- stream tiles with 1-deep prefetch ----
    bf16x8 cb0, cb1, nb0, nb1;
    LOAD_TILE(wx, cb0, cb1);

    #pragma unroll 1
    for (int t = wx; t < NTILE; t += NWX) {
        const int tn = (t + NWX < NTILE) ? (t + NWX) : t;   // clamped prefetch
        LOAD_TILE(tn, nb0, nb1);

        #pragma unroll
        for (int i = 0; i < PP; ++i) {
            // ---- layer 1: C1[h-packed row, a]; rows 4g+r in lane
            f32x4 c1 = b1v[i];
            c1 = __builtin_amdgcn_mfma_f32_16x16x32_bf16(w1a[i], cb0, c1, 0, 0, 0);
            c1 = __builtin_amdgcn_mfma_f32_16x16x32_bf16(w1b[i], cb1, c1, 0, 0, 0);

            f32x4 c2;
#if __has_builtin(__builtin_amdgcn_mfma_f32_16x16x16bf16_1k)
            // ---- layer 2: C1 output layout == 16x16x16 B-fragment layout
            union { unsigned u[2]; bf16x4 v; } pb;
            pb.u[0] = pack2bf(fmaxf(c1[0], 0.f), fmaxf(c1[1], 0.f));
            pb.u[1] = pack2bf(fmaxf(c1[2], 0.f), fmaxf(c1[3], 0.f));
            c2 = __builtin_amdgcn_mfma_f32_16x16x16bf16_1k(w2v[i], pb.v, b2v[i], 0, 0, 0);
#else
            // ---- fallback: redistribute rows 4g+r -> k=8g+j via shfl, x32 MFMA
            float rl[4];
            #pragma unroll
            for (int r = 0; r < 4; ++r) rl[r] = fmaxf(c1[r], 0.f);
            bf16x8 pb8;
            #pragma unroll
            for (int j = 0; j < 8; ++j) {
                const int src = ((2 * g + (j >> 2)) << 4) + col;
                pb8[j] = (short)f2bf(__shfl(rl[j & 3], src, 64));
            }
            bf16x8 w28;
            #pragma unroll
            for (int r = 0; r < 4; ++r) { w28[r] = w2v[i][r]; w28[r + 4] = 0; }
            c2 = __builtin_amdgcn_mfma_f32_16x16x32_bf16(w28, pb8, b2v[i], 0, 0, 0);
#endif
            // ---- layer 3: 4-row partial dot + partner combine (xor 16)
            float s;
            s = fmaf(fmaxf(c2[0], 0.f), w3v[i][0], 0.f);
            s = fmaf(fmaxf(c2[1], 0.f), w3v[i][1], s);
            s = fmaf(fmaxf(c2[2], 0.f), w3v[i][2], s);
            s = fmaf(fmaxf(c2[3], 0.f), w3v[i][3], s);
            const float tv = s + __shfl_xor(s, 16, 64);
            if (!(g & 1)) {
                const int pl = lane >> 5;               // 0: p even, 1: p odd
                out[(size_t)((ppbase + i) * 2 + pl) * NALL + t * 16 + col] =
                    tv + b3s[i];
            }
        }
        cb0 = nb0; cb1 = nb1;
    }
}

extern "C" void kernel_launch(void* const* d_in, const int* in_sizes, int n_in,
                              void* d_out, int out_size, void* d_ws, size_t ws_size,
                              hipStream_t stream) {
    const float* prop = (const float*)d_in[0];   // (128, 32)
    const float* allf = (const float*)d_in[1];   // (100000, 35)
    const float* W    = (const float*)d_in[2];   // (32, 369)
    const float* b    = (const float*)d_in[3];   // (369,)
    float* out = (float*)d_out;                  // (128, 100000, 1)
    char*  ws  = (char*)d_ws;

    prep_kernel<<<NPAIR, 256, 0, stream>>>(prop, W, b, ws);

    // 196 blocks (784 waves) stream the tile space; 16 pair-quarters in y
    dim3 grid(196, NPAIR / PP);
    mlp_kernel<<<grid, 256, 0, stream>>>(allf, ws, out);
}

// Round 9
// 126.028 us; speedup vs baseline: 1.1163x; 1.1163x over previous
//
#include <hip/hip_runtime.h>
#include <hip/hip_bf16.h>

#define IN_C  32
#define CH    35
#define P_CNT 369
#define NPAIR 64
#define NALL  100000
#define NTILE 6250          // NALL / 16 exactly
#define PP    4             // pairs per wave (grid.y = 64/PP = 16)
#define NWX   256           // waves per y-slice: grid.x(64) * 4 waves/block

// param offsets within a proposal's 369 floats
#define OW1 0               // w1[c][h] = c*8 + h   (c < 35)
#define OB1 280
#define OW2 288             // w2[h][k] = 288 + h*8 + k
#define OB2 352
#define OW3 360
#define OB3 368

// d_ws byte offsets
#define WS_W1F 0            // ushort [64 pair][2 kh][64 lane][8]   131072 B
#define WS_W2F 131072       // ushort [64][64 lane][4]              32768 B
#define WS_B2F 229376       // float  [64][64 lane][4]              65536 B
#define WS_W3F 294912       // float  [64][64 lane][4]              65536 B
#define WS_B3F 360448       // float  [64][2]                       512 B

typedef short  bf16x8 __attribute__((ext_vector_type(8)));
typedef short  bf16x4 __attribute__((ext_vector_type(4)));
typedef float  f32x4  __attribute__((ext_vector_type(4)));

static __device__ inline unsigned short f2bf(float x) {   // software RNE (prep + fallback)
    union { float f; unsigned u; } v; v.f = x;
    unsigned r = v.u + 0x7FFFu + ((v.u >> 16) & 1u);
    return (unsigned short)(r >> 16);
}

// API-sanctioned packed f32->bf16 RNE (native cvt on gfx950).
static __device__ inline unsigned pack2bf(float lo, float hi) {
    __hip_bfloat162 h2 = __float22bfloat162_rn(make_float2(lo, hi));
    union { __hip_bfloat162 h; unsigned u; } c; c.h = h2; return c.u;
}

// ---------------- Prep: params for one pair + lane-exact fragment packing ----
__global__ __launch_bounds__(256) void prep_kernel(
        const float* __restrict__ prop,   // (128, 32)
        const float* __restrict__ W,      // (32, 369)
        const float* __restrict__ b,      // (369,)
        char* __restrict__ ws) {
    const int pp  = blockIdx.x;           // pair index 0..63
    const int tid = threadIdx.x;
    __shared__ float P[2][P_CNT];

    for (int idx = tid; idx < 2 * P_CNT; idx += 256) {
        const int pl = (idx >= P_CNT) ? 1 : 0;
        const int j  = idx - pl * P_CNT;
        const float* pr = prop + (size_t)(2 * pp + pl) * IN_C;
        float acc = b[j];
        #pragma unroll
        for (int c = 0; c < IN_C; ++c)
            acc = fmaf(pr[c], W[(size_t)c * P_CNT + j], acc);
        P[pl][j] = acc;
    }
    __syncthreads();

    if (tid >= 64) return;
    const int lane = tid;
    const int g = lane >> 4;
    const int m = lane & 15;

    // W1F: A-frag of 16x16x32. A[m = h-packed][k = c]; lane: row=m, k=8g+j.
    // k == 35 carries b1 (feature slot 35 is a constant 1.0 in the B-frag),
    // folding the layer-1 bias into the MFMA: frees 4 VGPR/pair in mlp_kernel.
    {
        unsigned short* w1f = (unsigned short*)(ws + WS_W1F);
        const int pl = m >> 3, h = m & 7;
        #pragma unroll
        for (int kh = 0; kh < 2; ++kh)
            #pragma unroll
            for (int j = 0; j < 8; ++j) {
                const int c = kh * 32 + g * 8 + j;
                float v = 0.f;
                if (c < CH) v = P[pl][OW1 + c * 8 + h];
                else if (c == CH) v = P[pl][OB1 + h];          // bias column
                w1f[((size_t)(pp * 2 + kh) * 64 + lane) * 8 + j] = f2bf(v);
            }
    }
    // W2F: A-frag of 16x16x16 (block-diag packed w2). row=m, k=4g+r
    {
        unsigned short* w2f = (unsigned short*)(ws + WS_W2F);
        const int plj = m >> 3, jj = m & 7;
        #pragma unroll
        for (int r = 0; r < 4; ++r) {
            const int colh = g * 4 + r;
            const int ph = colh >> 3, h = colh & 7;
            const float v = (ph == plj) ? P[plj][OW2 + h * 8 + jj] : 0.f;
            w2f[((size_t)pp * 64 + lane) * 4 + r] = f2bf(v);
        }
    }
    // B2F / W3F: per-lane C-init rows (row = 4g + r, h/j-packed)
    {
        float* b2f = (float*)(ws + WS_B2F);
        float* w3f = (float*)(ws + WS_W3F);
        #pragma unroll
        for (int r = 0; r < 4; ++r) {
            const int row = g * 4 + r;
            b2f[((size_t)pp * 64 + lane) * 4 + r] = P[row >> 3][OB2 + (row & 7)];
            w3f[((size_t)pp * 64 + lane) * 4 + r] = P[row >> 3][OW3 + (row & 7)];
        }
    }
    if (lane < 2) ((float*)(ws + WS_B3F))[pp * 2 + lane] = P[lane][OB3];
}

// Load one 16-row feature tile's B-fragments for this lane.
// bf0: k = 8g+j (c 0..31); bf1: k = 32+8g+j — g==0 holds c 32..34 plus the
// constant 1.0 at k==35 that multiplies the bias column of W1F.
#define LOAD_TILE(T, O0, O1) do {                                             \
    const float* fr_ = allf + (size_t)((T) * 16 + col) * CH;                  \
    const float v0_ = fr_[g * 8 + 0], v1_ = fr_[g * 8 + 1];                   \
    const float v2_ = fr_[g * 8 + 2], v3_ = fr_[g * 8 + 3];                   \
    const float v4_ = fr_[g * 8 + 4], v5_ = fr_[g * 8 + 5];                   \
    const float v6_ = fr_[g * 8 + 6], v7_ = fr_[g * 8 + 7];                   \
    float e0_ = 0.f, e1_ = 0.f, e2_ = 0.f, e3_ = 0.f;                         \
    if (g == 0) { e0_ = fr_[32]; e1_ = fr_[33]; e2_ = fr_[34]; e3_ = 1.f; }   \
    union { unsigned u[4]; bf16x8 v; } A0_, A1_;                              \
    A0_.u[0] = pack2bf(v0_, v1_); A0_.u[1] = pack2bf(v2_, v3_);               \
    A0_.u[2] = pack2bf(v4_, v5_); A0_.u[3] = pack2bf(v6_, v7_);               \
    A1_.u[0] = pack2bf(e0_, e1_); A1_.u[1] = pack2bf(e2_, e3_);               \
    A1_.u[2] = 0u; A1_.u[3] = 0u;                                             \
    O0 = A0_.v; O1 = A1_.v; } while (0)

// ---------------- Main: weights-resident (PP pairs), persistent tile stream -
// __launch_bounds__(256, 4): 128-reg unified budget -> 4 waves/SIMD resident.
// (R6/R8's (256,2-3) granted 170-256 regs; compiler parked fragments in AGPRs
// and sized for 2 waves/SIMD -> 45% VALUBusy issue starvation.)
__global__ __launch_bounds__(256, 4) void mlp_kernel(
        const float* __restrict__ allf,   // (100000, 35)
        const char* __restrict__ ws,
        float* __restrict__ out) {        // (128, 100000)
    const int lane = threadIdx.x & 63;
    const int wave = threadIdx.x >> 6;
    const int wx   = blockIdx.x * 4 + wave;   // 0..NWX-1
    const int g    = lane >> 4;
    const int col  = lane & 15;
    const int ppbase = blockIdx.y * PP;

    const bf16x8* __restrict__ w1f = (const bf16x8*)(ws + WS_W1F);
    const bf16x4* __restrict__ w2f = (const bf16x4*)(ws + WS_W2F);
    const f32x4*  __restrict__ b2f = (const f32x4*)(ws + WS_B2F);
    const f32x4*  __restrict__ w3f = (const f32x4*)(ws + WS_W3F);
    const float*  __restrict__ b3f = (const float*)(ws + WS_B3F);

    // ---- resident weights for PP pairs (19 VGPR/pair = 76), loaded once ----
    bf16x8 w1a[PP], w1b[PP];
    bf16x4 w2v[PP];
    f32x4  b2v[PP], w3v[PP];
    float  b3s[PP];
    #pragma unroll
    for (int i = 0; i < PP; ++i) {
        const int pp = ppbase + i;
        w1a[i] = w1f[(pp * 2 + 0) * 64 + lane];
        w1b[i] = w1f[(pp * 2 + 1) * 64 + lane];
        w2v[i] = w2f[pp * 64 + lane];
        b2v[i] = b2f[pp * 64 + lane];
        w3v[i] = w3f[pp * 64 + lane];
        b3s[i] = b3f[pp * 2 + (lane >> 5)];
    }
    #pragma unroll
    for (int i = 0; i < PP; ++i)
        asm volatile("" : "+v"(w1a[i]), "+v"(w1b[i]), "+v"(w2v[i]),
                          "+v"(b2v[i]), "+v"(w3v[i]));

    if (wx >= NTILE) return;

    // ---- stream tiles with 1-deep prefetch ----
    bf16x8 cb0, cb1, nb0, nb1;
    LOAD_TILE(wx, cb0, cb1);

    #pragma unroll 1
    for (int t = wx; t < NTILE; t += NWX) {
        const int tn = (t + NWX < NTILE) ? (t + NWX) : t;   // clamped prefetch
        LOAD_TILE(tn, nb0, nb1);

        #pragma unroll
        for (int i = 0; i < PP; ++i) {
            // ---- layer 1 (+bias via k=35): C1[h-packed row, a]; rows 4g+r
            f32x4 c1 = {0.f, 0.f, 0.f, 0.f};
            c1 = __builtin_amdgcn_mfma_f32_16x16x32_bf16(w1a[i], cb0, c1, 0, 0, 0);
            c1 = __builtin_amdgcn_mfma_f32_16x16x32_bf16(w1b[i], cb1, c1, 0, 0, 0);

            f32x4 c2;
#if __has_builtin(__builtin_amdgcn_mfma_f32_16x16x16bf16_1k)
            // ---- layer 2: C1 output layout == 16x16x16 B-fragment layout
            union { unsigned u[2]; bf16x4 v; } pb;
            pb.u[0] = pack2bf(fmaxf(c1[0], 0.f), fmaxf(c1[1], 0.f));
            pb.u[1] = pack2bf(fmaxf(c1[2], 0.f), fmaxf(c1[3], 0.f));
            c2 = __builtin_amdgcn_mfma_f32_16x16x16bf16_1k(w2v[i], pb.v, b2v[i], 0, 0, 0);
#else
            // ---- fallback: redistribute rows 4g+r -> k=8g+j via shfl, x32 MFMA
            float rl[4];
            #pragma unroll
            for (int r = 0; r < 4; ++r) rl[r] = fmaxf(c1[r], 0.f);
            bf16x8 pb8;
            #pragma unroll
            for (int j = 0; j < 8; ++j) {
                const int src = ((2 * g + (j >> 2)) << 4) + col;
                pb8[j] = (short)f2bf(__shfl(rl[j & 3], src, 64));
            }
            bf16x8 w28;
            #pragma unroll
            for (int r = 0; r < 4; ++r) { w28[r] = w2v[i][r]; w28[r + 4] = 0; }
            c2 = __builtin_amdgcn_mfma_f32_16x16x32_bf16(w28, pb8, b2v[i], 0, 0, 0);
#endif
            // ---- layer 3: 4-row partial dot + partner combine (xor 16)
            float s;
            s = fmaf(fmaxf(c2[0], 0.f), w3v[i][0], 0.f);
            s = fmaf(fmaxf(c2[1], 0.f), w3v[i][1], s);
            s = fmaf(fmaxf(c2[2], 0.f), w3v[i][2], s);
            s = fmaf(fmaxf(c2[3], 0.f), w3v[i][3], s);
            const float tv = s + __shfl_xor(s, 16, 64);
            if (!(g & 1)) {
                const int pl = lane >> 5;               // 0: p even, 1: p odd
                out[(size_t)((ppbase + i) * 2 + pl) * NALL + t * 16 + col] =
                    tv + b3s[i];
            }
        }
        cb0 = nb0; cb1 = nb1;
    }
}

extern "C" void kernel_launch(void* const* d_in, const int* in_sizes, int n_in,
                              void* d_out, int out_size, void* d_ws, size_t ws_size,
                              hipStream_t stream) {
    const float* prop = (const float*)d_in[0];   // (128, 32)
    const float* allf = (const float*)d_in[1];   // (100000, 35)
    const float* W    = (const float*)d_in[2];   // (32, 369)
    const float* b    = (const float*)d_in[3];   // (369,)
    float* out = (float*)d_out;                  // (128, 100000, 1)
    char*  ws  = (char*)d_ws;

    prep_kernel<<<NPAIR, 256, 0, stream>>>(prop, W, b, ws);

    // Persistent: 64 blocks x 16 pair-quarters = 1024 blocks = exactly
    // 4 blocks/CU capacity at 4 waves/SIMD -> no dispatch tail.
    dim3 grid(64, NPAIR / PP);
    mlp_kernel<<<grid, 256, 0, stream>>>(allf, ws, out);
}